// Round 4
// baseline (307.913 us; speedup 1.0000x reference)
//
#include <hip/hip_runtime.h>

#define D 128
typedef unsigned short ushort_t;

// ---------------- helpers ----------------
__device__ __forceinline__ float wred_max(float v){
#pragma unroll
  for (int o = 1; o < 64; o <<= 1) v = fmaxf(v, __shfl_xor(v, o, 64));
  return v;
}
__device__ __forceinline__ float wred_sum(float v){
#pragma unroll
  for (int o = 1; o < 64; o <<= 1) v += __shfl_xor(v, o, 64);
  return v;
}
__device__ __forceinline__ unsigned short f2bf(float f){
  unsigned u = __float_as_uint(f);
  unsigned r = (u + 0x7FFFu + ((u >> 16) & 1u)) >> 16;   // RNE
  return (unsigned short)r;
}
__device__ __forceinline__ float bflo(unsigned u){ return __uint_as_float(u << 16); }
__device__ __forceinline__ float bfhi(unsigned u){ return __uint_as_float(u & 0xFFFF0000u); }

// ---------------- CSR build ----------------
__global__ __launch_bounds__(256) void k_zero(int* __restrict__ p, int n){
  int i = blockIdx.x * 256 + threadIdx.x;
  if (i < n) p[i] = 0;
}

__global__ __launch_bounds__(256) void k_hist(const int* __restrict__ dst, int E, int EP,
                                              int* __restrict__ counts){
  int e = blockIdx.x * blockDim.x + threadIdx.x;
  if (e >= EP) return;
  int d = (e < E) ? dst[e] : (e - E);   // tail = self loops
  atomicAdd(&counts[d], 1);
}

__global__ __launch_bounds__(256) void k_scan1(const int* __restrict__ counts, int n,
                                               int* __restrict__ excl, int* __restrict__ bsum){
  __shared__ int ws[4];
  int tid = threadIdx.x, lane = tid & 63, wid = tid >> 6;
  int i = blockIdx.x * 256 + tid;
  int v = (i < n) ? counts[i] : 0;
  int x = v;
#pragma unroll
  for (int o = 1; o < 64; o <<= 1){ int t = __shfl_up(x, o, 64); if (lane >= o) x += t; }
  if (lane == 63) ws[wid] = x;
  __syncthreads();
  int s0 = ws[0], s1 = ws[1], s2 = ws[2];
  int wo = (wid > 0 ? s0 : 0) + (wid > 1 ? s1 : 0) + (wid > 2 ? s2 : 0);
  if (i < n) excl[i] = wo + x - v;
  if (tid == 255) bsum[blockIdx.x] = wo + x;
}
__global__ __launch_bounds__(256) void k_scan2(int* __restrict__ bsum, int nb){
  __shared__ int ws[4];
  int tid = threadIdx.x, lane = tid & 63, wid = tid >> 6;
  int v = (tid < nb) ? bsum[tid] : 0;
  int x = v;
#pragma unroll
  for (int o = 1; o < 64; o <<= 1){ int t = __shfl_up(x, o, 64); if (lane >= o) x += t; }
  if (lane == 63) ws[wid] = x;
  __syncthreads();
  int s0 = ws[0], s1 = ws[1], s2 = ws[2];
  int wo = (wid > 0 ? s0 : 0) + (wid > 1 ? s1 : 0) + (wid > 2 ? s2 : 0);
  if (tid < nb) bsum[tid] = wo + x - v;
}
__global__ __launch_bounds__(256) void k_scan3(int* __restrict__ rowptr, const int* __restrict__ bsum,
                                               int* __restrict__ cursor, int n, int total){
  int i = blockIdx.x * 256 + threadIdx.x;
  if (i < n){
    int v = rowptr[i] + bsum[blockIdx.x];
    rowptr[i] = v;
    cursor[i] = v;
  }
  if (i == 0) rowptr[n] = total;
}

__global__ __launch_bounds__(256) void k_fill(const int* __restrict__ src, const int* __restrict__ dst,
                                              int E, int EP,
                                              int* __restrict__ cursor, ushort_t* __restrict__ csr){
  int e = blockIdx.x * blockDim.x + threadIdx.x;
  if (e >= EP) return;
  int s, d;
  if (e < E){ s = src[e]; d = dst[e]; } else { s = d = e - E; }
  int pos = atomicAdd(&cursor[d], 1);
  csr[pos] = (ushort_t)s;
}

// ---------------- GEMM + fused attention dots ----------------
// h(bf16)[n x 128] = A @ W; as_[r]=h_f32[r]·a_src; ad_[r]=h_f32[r]·a_dst
template<bool ABF16>
__global__ __launch_bounds__(256) void k_gemm_dots(const void* __restrict__ Av,
                                                   const float* __restrict__ W,
                                                   const float* __restrict__ a_src,
                                                   const float* __restrict__ a_dst,
                                                   ushort_t* __restrict__ Hbf,
                                                   float* __restrict__ as_,
                                                   float* __restrict__ ad_,
                                                   int n){
  __shared__ float sW[128][128];   // 64 KB
  int tid = threadIdx.x;
  int r0 = blockIdx.x * 128;
  int tx = tid & 15;               // col groups: tx*4 and tx*4+64
  int ty = tid >> 4;               // row group: ty*8 .. ty*8+7

#pragma unroll
  for (int i = 0; i < 16; i++){
    int slot = tid + i * 256;
    int k = slot >> 5, cq = slot & 31;
    *(float4*)&sW[k][cq * 4] = *(const float4*)&W[(size_t)k * D + cq * 4];
  }
  __syncthreads();

  float4 acc0[8], acc1[8];
#pragma unroll
  for (int i = 0; i < 8; i++){ acc0[i] = make_float4(0,0,0,0); acc1[i] = make_float4(0,0,0,0); }

  if (ABF16){
    const ushort_t* ap[8];
#pragma unroll
    for (int i = 0; i < 8; i++){
      int gr = r0 + ty * 8 + i; if (gr > n - 1) gr = n - 1;
      ap[i] = (const ushort_t*)Av + (size_t)gr * D;
    }
    for (int k8 = 0; k8 < 128; k8 += 8){
      uint4 raw[8];
#pragma unroll
      for (int i = 0; i < 8; i++) raw[i] = *(const uint4*)(ap[i] + k8);
#pragma unroll
      for (int kk = 0; kk < 8; kk++){
        float4 w0 = *(const float4*)&sW[k8 + kk][tx * 4];
        float4 w1 = *(const float4*)&sW[k8 + kk][tx * 4 + 64];
#pragma unroll
        for (int i = 0; i < 8; i++){
          unsigned word = (&raw[i].x)[kk >> 1];
          float a = (kk & 1) ? bfhi(word) : bflo(word);
          acc0[i].x += a * w0.x; acc0[i].y += a * w0.y; acc0[i].z += a * w0.z; acc0[i].w += a * w0.w;
          acc1[i].x += a * w1.x; acc1[i].y += a * w1.y; acc1[i].z += a * w1.z; acc1[i].w += a * w1.w;
        }
      }
    }
  } else {
    const float* ap[8];
#pragma unroll
    for (int i = 0; i < 8; i++){
      int gr = r0 + ty * 8 + i; if (gr > n - 1) gr = n - 1;
      ap[i] = (const float*)Av + (size_t)gr * D;
    }
#pragma unroll 2
    for (int k4 = 0; k4 < 128; k4 += 4){
      float4 av[8];
#pragma unroll
      for (int i = 0; i < 8; i++) av[i] = *(const float4*)(ap[i] + k4);
#pragma unroll
      for (int kk = 0; kk < 4; kk++){
        float4 w0 = *(const float4*)&sW[k4 + kk][tx * 4];
        float4 w1 = *(const float4*)&sW[k4 + kk][tx * 4 + 64];
#pragma unroll
        for (int i = 0; i < 8; i++){
          float a = (kk == 0) ? av[i].x : (kk == 1) ? av[i].y : (kk == 2) ? av[i].z : av[i].w;
          acc0[i].x += a * w0.x; acc0[i].y += a * w0.y; acc0[i].z += a * w0.z; acc0[i].w += a * w0.w;
          acc1[i].x += a * w1.x; acc1[i].y += a * w1.y; acc1[i].z += a * w1.z; acc1[i].w += a * w1.w;
        }
      }
    }
  }

  // fused dots
  float4 s0 = *(const float4*)&a_src[tx * 4];
  float4 s1 = *(const float4*)&a_src[tx * 4 + 64];
  float4 d0 = *(const float4*)&a_dst[tx * 4];
  float4 d1 = *(const float4*)&a_dst[tx * 4 + 64];
  float ps[8], pd[8];
#pragma unroll
  for (int i = 0; i < 8; i++){
    ps[i] = acc0[i].x*s0.x + acc0[i].y*s0.y + acc0[i].z*s0.z + acc0[i].w*s0.w
          + acc1[i].x*s1.x + acc1[i].y*s1.y + acc1[i].z*s1.z + acc1[i].w*s1.w;
    pd[i] = acc0[i].x*d0.x + acc0[i].y*d0.y + acc0[i].z*d0.z + acc0[i].w*d0.w
          + acc1[i].x*d1.x + acc1[i].y*d1.y + acc1[i].z*d1.z + acc1[i].w*d1.w;
  }
#pragma unroll
  for (int o = 1; o < 16; o <<= 1){
#pragma unroll
    for (int i = 0; i < 8; i++){
      ps[i] += __shfl_xor(ps[i], o, 64);
      pd[i] += __shfl_xor(pd[i], o, 64);
    }
  }
#pragma unroll
  for (int i = 0; i < 8; i++){
    int r = r0 + ty * 8 + i;
    bool ok = (r < n);
    if (ok && tx == i)     as_[r] = ps[i];
    if (ok && tx == 8 + i) ad_[r] = pd[i];
  }

#pragma unroll
  for (int i = 0; i < 8; i++){
    int r = r0 + ty * 8 + i;
    if (r < n){
      ushort4 u0, u1;
      u0.x = f2bf(acc0[i].x); u0.y = f2bf(acc0[i].y); u0.z = f2bf(acc0[i].z); u0.w = f2bf(acc0[i].w);
      u1.x = f2bf(acc1[i].x); u1.y = f2bf(acc1[i].y); u1.z = f2bf(acc1[i].z); u1.w = f2bf(acc1[i].w);
      *(ushort4*)&Hbf[(size_t)r * D + tx * 4]      = u0;
      *(ushort4*)&Hbf[(size_t)r * D + tx * 4 + 64] = u1;
    }
  }
}

// ---------------- aggregation: one wave per dst node, paired uint2 gather ----------------
template<bool OUTBF>
__global__ __launch_bounds__(256) void k_agg(const uint2* __restrict__ hb2,
                                             const ushort_t* __restrict__ csr,
                                             const int* __restrict__ rowptr,
                                             const float* __restrict__ asrc,
                                             const float* __restrict__ adst,
                                             const float* __restrict__ bias,
                                             ushort_t* __restrict__ outb,
                                             float* __restrict__ outf,
                                             int relu, int n){
  int node = (blockIdx.x * 256 + threadIdx.x) >> 6;
  if (node >= n) return;
  int lane = threadIdx.x & 63;
  int ll = lane & 31, half = lane >> 5;
  int beg = rowptr[node];
  int deg = rowptr[node + 1] - beg;
  float adn = adst[node];
  float4 acc = make_float4(0.f, 0.f, 0.f, 0.f);
  float inv;

  if (deg <= 64){
    int s = 0; float logit = -1e30f;
    if (lane < deg){
      s = csr[beg + lane];
      float xx = asrc[s] + adn;
      logit = xx >= 0.f ? xx : 0.2f * xx;
    }
    float m = wred_max(logit);
    float p = (lane < deg) ? __expf(logit - m) : 0.f;
    float denom = wred_sum(p);
    inv = 1.f / (denom + 1e-16f);
    int j = 0;
    for (; j + 4 <= deg; j += 4){
      int sA = __shfl(s, j, 64),     sB = __shfl(s, j + 1, 64);
      int sC = __shfl(s, j + 2, 64), sD = __shfl(s, j + 3, 64);
      float aA = __shfl(p, j, 64),     aB = __shfl(p, j + 1, 64);
      float aC = __shfl(p, j + 2, 64), aD = __shfl(p, j + 3, 64);
      int   r0 = half ? sB : sA;  float w0 = half ? aB : aA;
      int   r1 = half ? sD : sC;  float w1 = half ? aD : aC;
      uint2 v0 = hb2[(size_t)r0 * 32 + ll];
      uint2 v1 = hb2[(size_t)r1 * 32 + ll];
      acc.x += w0 * bflo(v0.x); acc.y += w0 * bfhi(v0.x);
      acc.z += w0 * bflo(v0.y); acc.w += w0 * bfhi(v0.y);
      acc.x += w1 * bflo(v1.x); acc.y += w1 * bfhi(v1.x);
      acc.z += w1 * bflo(v1.y); acc.w += w1 * bfhi(v1.y);
    }
    for (; j < deg; j += 2){
      int sA = __shfl(s, j, 64);
      int sB = (j + 1 < deg) ? __shfl(s, j + 1, 64) : sA;
      float aA = __shfl(p, j, 64);
      float aB = (j + 1 < deg) ? __shfl(p, j + 1, 64) : 0.f;
      int r0 = half ? sB : sA;  float w0 = half ? aB : aA;
      uint2 v0 = hb2[(size_t)r0 * 32 + ll];
      acc.x += w0 * bflo(v0.x); acc.y += w0 * bfhi(v0.x);
      acc.z += w0 * bflo(v0.y); acc.w += w0 * bfhi(v0.y);
    }
  } else {
    // chunked path (deg > 64)
    float m = -1e30f;
    for (int base = 0; base < deg; base += 64){
      float l = -1e30f;
      int idx = base + lane;
      if (idx < deg){ int sx = csr[beg + idx]; float xx = asrc[sx] + adn; l = xx >= 0.f ? xx : 0.2f * xx; }
      m = fmaxf(m, wred_max(l));
    }
    float denom = 0.f;
    for (int base = 0; base < deg; base += 64){
      float p2 = 0.f;
      int idx = base + lane;
      if (idx < deg){ int sx = csr[beg + idx]; float xx = asrc[sx] + adn; float l = xx >= 0.f ? xx : 0.2f * xx; p2 = __expf(l - m); }
      denom += wred_sum(p2);
    }
    inv = 1.f / (denom + 1e-16f);
    for (int base = 0; base < deg; base += 64){
      int cnt = deg - base; if (cnt > 64) cnt = 64;
      float p2 = 0.f; int sx = 0;
      int idx = base + lane;
      if (idx < deg){ sx = csr[beg + idx]; float xx = asrc[sx] + adn; float l = xx >= 0.f ? xx : 0.2f * xx; p2 = __expf(l - m); }
      for (int j = 0; j < cnt; j += 2){
        int sA = __shfl(sx, j, 64);
        int sB = (j + 1 < cnt) ? __shfl(sx, j + 1, 64) : sA;
        float aA = __shfl(p2, j, 64);
        float aB = (j + 1 < cnt) ? __shfl(p2, j + 1, 64) : 0.f;
        int r0 = half ? sB : sA;  float w0 = half ? aB : aA;
        uint2 v0 = hb2[(size_t)r0 * 32 + ll];
        acc.x += w0 * bflo(v0.x); acc.y += w0 * bfhi(v0.x);
        acc.z += w0 * bflo(v0.y); acc.w += w0 * bfhi(v0.y);
      }
    }
  }
  // combine half-wave partial sums
  acc.x += __shfl_xor(acc.x, 32, 64);
  acc.y += __shfl_xor(acc.y, 32, 64);
  acc.z += __shfl_xor(acc.z, 32, 64);
  acc.w += __shfl_xor(acc.w, 32, 64);

  if (half == 0){
    float4 b4 = *(const float4*)&bias[ll * 4];
    float o0 = acc.x * inv + b4.x, o1 = acc.y * inv + b4.y;
    float o2 = acc.z * inv + b4.z, o3 = acc.w * inv + b4.w;
    if (relu){ o0 = fmaxf(o0, 0.f); o1 = fmaxf(o1, 0.f); o2 = fmaxf(o2, 0.f); o3 = fmaxf(o3, 0.f); }
    if (OUTBF){
      ushort4 u; u.x = f2bf(o0); u.y = f2bf(o1); u.z = f2bf(o2); u.w = f2bf(o3);
      *(ushort4*)&outb[(size_t)node * D + ll * 4] = u;
    } else {
      *(float4*)&outf[(size_t)node * D + ll * 4] = make_float4(o0, o1, o2, o3);
    }
  }
}

// ---------------- fused pool + final linear ----------------
__device__ __forceinline__ int lbound(const int* a, int n, int key){
  int lo = 0, hi = n;
  while (lo < hi){ int mid = (lo + hi) >> 1; if (a[mid] < key) lo = mid + 1; else hi = mid; }
  return lo;
}

__global__ __launch_bounds__(128) void k_pool_final(const float* __restrict__ x,
                                                    const int* __restrict__ batch,
                                                    const float* __restrict__ Wl,
                                                    const float* __restrict__ bl,
                                                    float* __restrict__ out, int n){
  __shared__ float pl[128];
  int g = blockIdx.x;
  int c = threadIdx.x;
  int lo = lbound(batch, n, g);
  int hi = lbound(batch, n, g + 1);
  float sum = 0.f;
  for (int i = lo; i < hi; i++) sum += x[(size_t)i * D + c];
  float cnt = (float)(hi - lo);
  pl[c] = sum / fmaxf(cnt, 1.f);
  __syncthreads();
  float acc = bl[c];
#pragma unroll 4
  for (int k = 0; k < 128; k++) acc += pl[k] * Wl[(size_t)k * D + c];
  out[(size_t)g * D + c] = acc;
}

// ---------------- launch ----------------
extern "C" void kernel_launch(void* const* d_in, const int* in_sizes, int n_in,
                              void* d_out, int out_size, void* d_ws, size_t ws_size,
                              hipStream_t stream){
  const float* x     = (const float*)d_in[0];
  const int*   ei    = (const int*)d_in[1];
  const int*   batch = (const int*)d_in[3];
  const float* gW[3]  = {(const float*)d_in[4],  (const float*)d_in[8],  (const float*)d_in[12]};
  const float* gAs[3] = {(const float*)d_in[5],  (const float*)d_in[9],  (const float*)d_in[13]};
  const float* gAd[3] = {(const float*)d_in[6],  (const float*)d_in[10], (const float*)d_in[14]};
  const float* gB[3]  = {(const float*)d_in[7],  (const float*)d_in[11], (const float*)d_in[15]};
  const float* linW = (const float*)d_in[16];
  const float* linB = (const float*)d_in[17];
  float* outp = (float*)d_out;

  int N  = in_sizes[3];
  int E  = in_sizes[1] / 2;
  int EP = E + N;
  int G  = out_size / D;

  char* ws = (char*)d_ws;
  size_t off = 0;
  auto alloc = [&](size_t bytes)->void*{
    void* p = ws + off;
    off += (bytes + 255) & ~(size_t)255;
    return p;
  };
  float*    bufF   = (float*)alloc((size_t)N * D * 4);      // layer-3 agg out (fp32)
  ushort_t* bufB   = (ushort_t*)alloc((size_t)N * D * 2);   // layer-1/2 agg out (bf16)
  ushort_t* Hbf    = (ushort_t*)alloc((size_t)N * D * 2);   // h (bf16)
  float*    as_    = (float*)alloc((size_t)N * 4);
  float*    ad_    = (float*)alloc((size_t)N * 4);
  int*      counts = (int*)  alloc((size_t)N * 4);
  int*      cursor = (int*)  alloc((size_t)N * 4);
  int*      rowptr = (int*)  alloc((size_t)(N + 1) * 4);
  ushort_t* csr    = (ushort_t*)alloc((size_t)EP * 2);
  int*      bsum   = (int*)  alloc(1024 * 4);
  (void)ws_size; (void)n_in;

  const int* esrc = ei;
  const int* edst = ei + E;

  int tpb = 256;
  int egrid = (EP + tpb - 1) / tpb;
  int ngrid = (N + tpb - 1) / tpb;

  k_zero <<<ngrid, tpb, 0, stream>>>(counts, N);
  k_hist <<<egrid, tpb, 0, stream>>>(edst, E, EP, counts);
  k_scan1<<<ngrid, tpb, 0, stream>>>(counts, N, rowptr, bsum);
  k_scan2<<<1,     tpb, 0, stream>>>(bsum, ngrid);
  k_scan3<<<ngrid, tpb, 0, stream>>>(rowptr, bsum, cursor, N, EP);
  k_fill <<<egrid, tpb, 0, stream>>>(esrc, edst, E, EP, cursor, csr);

  int gemm_grid = (N + 127) / 128;
  int node_grid = (N + 3) / 4;
  const uint2* hbu = (const uint2*)Hbf;

  // layer 1 (fp32 in, bf16 out)
  k_gemm_dots<false><<<gemm_grid, tpb, 0, stream>>>(x, gW[0], gAs[0], gAd[0], Hbf, as_, ad_, N);
  k_agg<true>       <<<node_grid, tpb, 0, stream>>>(hbu, csr, rowptr, as_, ad_, gB[0], bufB, nullptr, 1, N);
  // layer 2 (bf16 in, bf16 out)
  k_gemm_dots<true> <<<gemm_grid, tpb, 0, stream>>>(bufB, gW[1], gAs[1], gAd[1], Hbf, as_, ad_, N);
  k_agg<true>       <<<node_grid, tpb, 0, stream>>>(hbu, csr, rowptr, as_, ad_, gB[1], bufB, nullptr, 1, N);
  // layer 3 (bf16 in, fp32 out)
  k_gemm_dots<true> <<<gemm_grid, tpb, 0, stream>>>(bufB, gW[2], gAs[2], gAd[2], Hbf, as_, ad_, N);
  k_agg<false>      <<<node_grid, tpb, 0, stream>>>(hbu, csr, rowptr, as_, ad_, gB[2], nullptr, bufF, 0, N);

  // fused pool + final linear
  k_pool_final<<<G, 128, 0, stream>>>(bufF, batch, linW, linB, outp, N);
}

// Round 5
// 262.688 us; speedup vs baseline: 1.1722x; 1.1722x over previous
//
#include <hip/hip_runtime.h>

#define D 128
typedef unsigned short ushort_t;
typedef __attribute__((ext_vector_type(8))) short bf16x8;
typedef __attribute__((ext_vector_type(4))) float f32x4;

// ---------------- helpers ----------------
__device__ __forceinline__ float wred_max(float v){
#pragma unroll
  for (int o = 1; o < 64; o <<= 1) v = fmaxf(v, __shfl_xor(v, o, 64));
  return v;
}
__device__ __forceinline__ float wred_sum(float v){
#pragma unroll
  for (int o = 1; o < 64; o <<= 1) v += __shfl_xor(v, o, 64);
  return v;
}
__device__ __forceinline__ unsigned short f2bf(float f){
  unsigned u = __float_as_uint(f);
  unsigned r = (u + 0x7FFFu + ((u >> 16) & 1u)) >> 16;   // RNE
  return (unsigned short)r;
}
__device__ __forceinline__ float bflo(unsigned u){ return __uint_as_float(u << 16); }
__device__ __forceinline__ float bfhi(unsigned u){ return __uint_as_float(u & 0xFFFF0000u); }

// ---------------- CSR build ----------------
__global__ __launch_bounds__(256) void k_zero(int* __restrict__ p, int n){
  int i = blockIdx.x * 256 + threadIdx.x;
  if (i < n) p[i] = 0;
}

__global__ __launch_bounds__(256) void k_hist(const int* __restrict__ dst, int E, int EP,
                                              int* __restrict__ counts){
  int e = blockIdx.x * blockDim.x + threadIdx.x;
  if (e >= EP) return;
  int d = (e < E) ? dst[e] : (e - E);   // tail = self loops
  atomicAdd(&counts[d], 1);
}

__global__ __launch_bounds__(256) void k_scan1(const int* __restrict__ counts, int n,
                                               int* __restrict__ excl, int* __restrict__ bsum){
  __shared__ int ws[4];
  int tid = threadIdx.x, lane = tid & 63, wid = tid >> 6;
  int i = blockIdx.x * 256 + tid;
  int v = (i < n) ? counts[i] : 0;
  int x = v;
#pragma unroll
  for (int o = 1; o < 64; o <<= 1){ int t = __shfl_up(x, o, 64); if (lane >= o) x += t; }
  if (lane == 63) ws[wid] = x;
  __syncthreads();
  int s0 = ws[0], s1 = ws[1], s2 = ws[2];
  int wo = (wid > 0 ? s0 : 0) + (wid > 1 ? s1 : 0) + (wid > 2 ? s2 : 0);
  if (i < n) excl[i] = wo + x - v;
  if (tid == 255) bsum[blockIdx.x] = wo + x;
}
__global__ __launch_bounds__(256) void k_scan2(int* __restrict__ bsum, int nb){
  __shared__ int ws[4];
  int tid = threadIdx.x, lane = tid & 63, wid = tid >> 6;
  int v = (tid < nb) ? bsum[tid] : 0;
  int x = v;
#pragma unroll
  for (int o = 1; o < 64; o <<= 1){ int t = __shfl_up(x, o, 64); if (lane >= o) x += t; }
  if (lane == 63) ws[wid] = x;
  __syncthreads();
  int s0 = ws[0], s1 = ws[1], s2 = ws[2];
  int wo = (wid > 0 ? s0 : 0) + (wid > 1 ? s1 : 0) + (wid > 2 ? s2 : 0);
  if (tid < nb) bsum[tid] = wo + x - v;
}
__global__ __launch_bounds__(256) void k_scan3(int* __restrict__ rowptr, const int* __restrict__ bsum,
                                               int* __restrict__ cursor, int n, int total){
  int i = blockIdx.x * 256 + threadIdx.x;
  if (i < n){
    int v = rowptr[i] + bsum[blockIdx.x];
    rowptr[i] = v;
    cursor[i] = v;
  }
  if (i == 0) rowptr[n] = total;
}

__global__ __launch_bounds__(256) void k_fill(const int* __restrict__ src, const int* __restrict__ dst,
                                              int E, int EP,
                                              int* __restrict__ cursor, ushort_t* __restrict__ csr){
  int e = blockIdx.x * blockDim.x + threadIdx.x;
  if (e >= EP) return;
  int s, d;
  if (e < E){ s = src[e]; d = dst[e]; } else { s = d = e - E; }
  int pos = atomicAdd(&cursor[d], 1);
  csr[pos] = (ushort_t)s;
}

// ---------------- W pack: fp32 W -> (hi,lo) bf16 in B-fragment layout ----------------
// B frag for 16x16x32: lane l holds B[k][c] with c = ct*16 + (l&15), k = s*32 + (l>>4)*8 + e.
// pack offset = ((ct*4 + s)*64 + lane)*8 + e ; hi at [0..16383], lo at [16384..]
__global__ __launch_bounds__(256) void k_packW(const float* __restrict__ W,
                                               ushort_t* __restrict__ Wp){
  int idx = blockIdx.x * 256 + threadIdx.x;
  if (idx >= 16384) return;
  int k = idx >> 7, c = idx & 127;
  float w = W[idx];
  unsigned short hi = f2bf(w);
  float r = w - __uint_as_float((unsigned)hi << 16);
  unsigned short lo = f2bf(r);
  int ct = c >> 4, s = k >> 5, lane = (c & 15) | (((k >> 3) & 3) << 4), e = k & 7;
  int off = ((ct * 4 + s) * 64 + lane) * 8 + e;
  Wp[off] = hi;
  Wp[16384 + off] = lo;
}

// ---------------- MFMA GEMM + fused attention dots ----------------
// h(bf16)[n x 128] = A @ (W_hi + W_lo); as_[r]=h·a_src; ad_[r]=h·a_dst
// XF32: A is fp32 (split in-register into hi+lo bf16, 3 mfma passes), else A bf16 (2 passes).
template<bool XF32>
__global__ __launch_bounds__(256) void k_gemm_mfma(const void* __restrict__ Av,
                                                   const ushort_t* __restrict__ Wp,
                                                   const float* __restrict__ a_src,
                                                   const float* __restrict__ a_dst,
                                                   ushort_t* __restrict__ Hbf,
                                                   float* __restrict__ as_,
                                                   float* __restrict__ ad_,
                                                   int n){
  int tid = threadIdx.x;
  int wid = tid >> 6, l = tid & 63;
  int kg = l >> 4, cin = l & 15;
  int r0 = blockIdx.x * 64 + wid * 16;
  int row_l = r0 + cin;                 // A-fragment row for this lane (A: row=lane&15)
  if (row_l > n - 1) row_l = n - 1;

  // A fragments: k = s*32 + kg*8 + e
  bf16x8 ah[4], al[4];
  if (XF32){
    const float* xp = (const float*)Av + (size_t)row_l * D + kg * 8;
#pragma unroll
    for (int s = 0; s < 4; s++){
      float4 f0 = *(const float4*)(xp + s * 32);
      float4 f1 = *(const float4*)(xp + s * 32 + 4);
      float fv[8] = {f0.x, f0.y, f0.z, f0.w, f1.x, f1.y, f1.z, f1.w};
#pragma unroll
      for (int e = 0; e < 8; e++){
        unsigned short h = f2bf(fv[e]);
        ah[s][e] = (short)h;
        float r = fv[e] - __uint_as_float((unsigned)h << 16);
        al[s][e] = (short)f2bf(r);
      }
    }
  } else {
    const ushort_t* xp = (const ushort_t*)Av + (size_t)row_l * D + kg * 8;
#pragma unroll
    for (int s = 0; s < 4; s++) ah[s] = *(const bf16x8*)(xp + s * 32);
  }

  const bf16x8* Bh = (const bf16x8*)Wp;             // [(ct*4+s)*64 + lane]
  const bf16x8* Bl = (const bf16x8*)(Wp + 16384);

  f32x4 acc[8];
#pragma unroll
  for (int ct = 0; ct < 8; ct++) acc[ct] = (f32x4){0.f, 0.f, 0.f, 0.f};

#pragma unroll
  for (int ct = 0; ct < 8; ct++){
#pragma unroll
    for (int s = 0; s < 4; s++){
      bf16x8 bh = Bh[(ct * 4 + s) * 64 + l];
      bf16x8 bl = Bl[(ct * 4 + s) * 64 + l];
      acc[ct] = __builtin_amdgcn_mfma_f32_16x16x32_bf16(ah[s], bh, acc[ct], 0, 0, 0);
      acc[ct] = __builtin_amdgcn_mfma_f32_16x16x32_bf16(ah[s], bl, acc[ct], 0, 0, 0);
      if (XF32)
        acc[ct] = __builtin_amdgcn_mfma_f32_16x16x32_bf16(al[s], bh, acc[ct], 0, 0, 0);
    }
  }

  // epilogue: C[row=kg*4+j][col=ct*16+cin] = acc[ct][j]
  float asv[8], adv[8];
#pragma unroll
  for (int ct = 0; ct < 8; ct++){
    asv[ct] = a_src[ct * 16 + cin];
    adv[ct] = a_dst[ct * 16 + cin];
  }
#pragma unroll
  for (int j = 0; j < 4; j++){
    float ps = 0.f, pd = 0.f;
#pragma unroll
    for (int ct = 0; ct < 8; ct++){ ps += acc[ct][j] * asv[ct]; pd += acc[ct][j] * adv[ct]; }
#pragma unroll
    for (int o = 1; o < 16; o <<= 1){ ps += __shfl_xor(ps, o, 64); pd += __shfl_xor(pd, o, 64); }
    int row = r0 + kg * 4 + j;
    if (row < n){
      if (cin == 0) as_[row] = ps;
      if (cin == 1) ad_[row] = pd;
#pragma unroll
      for (int ct = 0; ct < 8; ct++)
        Hbf[(size_t)row * D + ct * 16 + cin] = f2bf(acc[ct][j]);
    }
  }
}

// ---------------- aggregation: one wave per dst node, paired uint2 gather ----------------
template<bool OUTBF>
__global__ __launch_bounds__(256) void k_agg(const uint2* __restrict__ hb2,
                                             const ushort_t* __restrict__ csr,
                                             const int* __restrict__ rowptr,
                                             const float* __restrict__ asrc,
                                             const float* __restrict__ adst,
                                             const float* __restrict__ bias,
                                             ushort_t* __restrict__ outb,
                                             float* __restrict__ outf,
                                             int relu, int n){
  int node = (blockIdx.x * 256 + threadIdx.x) >> 6;
  if (node >= n) return;
  int lane = threadIdx.x & 63;
  int ll = lane & 31, half = lane >> 5;
  int beg = rowptr[node];
  int deg = rowptr[node + 1] - beg;
  float adn = adst[node];
  float4 acc = make_float4(0.f, 0.f, 0.f, 0.f);
  float inv;

  if (deg <= 64){
    int s = 0; float logit = -1e30f;
    if (lane < deg){
      s = csr[beg + lane];
      float xx = asrc[s] + adn;
      logit = xx >= 0.f ? xx : 0.2f * xx;
    }
    float m = wred_max(logit);
    float p = (lane < deg) ? __expf(logit - m) : 0.f;
    float denom = wred_sum(p);
    inv = 1.f / (denom + 1e-16f);
    int j = 0;
    for (; j + 4 <= deg; j += 4){
      int sA = __shfl(s, j, 64),     sB = __shfl(s, j + 1, 64);
      int sC = __shfl(s, j + 2, 64), sD = __shfl(s, j + 3, 64);
      float aA = __shfl(p, j, 64),     aB = __shfl(p, j + 1, 64);
      float aC = __shfl(p, j + 2, 64), aD = __shfl(p, j + 3, 64);
      int   r0 = half ? sB : sA;  float w0 = half ? aB : aA;
      int   r1 = half ? sD : sC;  float w1 = half ? aD : aC;
      uint2 v0 = hb2[(size_t)r0 * 32 + ll];
      uint2 v1 = hb2[(size_t)r1 * 32 + ll];
      acc.x += w0 * bflo(v0.x); acc.y += w0 * bfhi(v0.x);
      acc.z += w0 * bflo(v0.y); acc.w += w0 * bfhi(v0.y);
      acc.x += w1 * bflo(v1.x); acc.y += w1 * bfhi(v1.x);
      acc.z += w1 * bflo(v1.y); acc.w += w1 * bfhi(v1.y);
    }
    for (; j < deg; j += 2){
      int sA = __shfl(s, j, 64);
      int sB = (j + 1 < deg) ? __shfl(s, j + 1, 64) : sA;
      float aA = __shfl(p, j, 64);
      float aB = (j + 1 < deg) ? __shfl(p, j + 1, 64) : 0.f;
      int r0 = half ? sB : sA;  float w0 = half ? aB : aA;
      uint2 v0 = hb2[(size_t)r0 * 32 + ll];
      acc.x += w0 * bflo(v0.x); acc.y += w0 * bfhi(v0.x);
      acc.z += w0 * bflo(v0.y); acc.w += w0 * bfhi(v0.y);
    }
  } else {
    float m = -1e30f;
    for (int base = 0; base < deg; base += 64){
      float l = -1e30f;
      int idx = base + lane;
      if (idx < deg){ int sx = csr[beg + idx]; float xx = asrc[sx] + adn; l = xx >= 0.f ? xx : 0.2f * xx; }
      m = fmaxf(m, wred_max(l));
    }
    float denom = 0.f;
    for (int base = 0; base < deg; base += 64){
      float p2 = 0.f;
      int idx = base + lane;
      if (idx < deg){ int sx = csr[beg + idx]; float xx = asrc[sx] + adn; float l = xx >= 0.f ? xx : 0.2f * xx; p2 = __expf(l - m); }
      denom += wred_sum(p2);
    }
    inv = 1.f / (denom + 1e-16f);
    for (int base = 0; base < deg; base += 64){
      int cnt = deg - base; if (cnt > 64) cnt = 64;
      float p2 = 0.f; int sx = 0;
      int idx = base + lane;
      if (idx < deg){ sx = csr[beg + idx]; float xx = asrc[sx] + adn; float l = xx >= 0.f ? xx : 0.2f * xx; p2 = __expf(l - m); }
      for (int j = 0; j < cnt; j += 2){
        int sA = __shfl(sx, j, 64);
        int sB = (j + 1 < cnt) ? __shfl(sx, j + 1, 64) : sA;
        float aA = __shfl(p2, j, 64);
        float aB = (j + 1 < cnt) ? __shfl(p2, j + 1, 64) : 0.f;
        int r0 = half ? sB : sA;  float w0 = half ? aB : aA;
        uint2 v0 = hb2[(size_t)r0 * 32 + ll];
        acc.x += w0 * bflo(v0.x); acc.y += w0 * bfhi(v0.x);
        acc.z += w0 * bflo(v0.y); acc.w += w0 * bfhi(v0.y);
      }
    }
  }
  acc.x += __shfl_xor(acc.x, 32, 64);
  acc.y += __shfl_xor(acc.y, 32, 64);
  acc.z += __shfl_xor(acc.z, 32, 64);
  acc.w += __shfl_xor(acc.w, 32, 64);

  if (half == 0){
    float4 b4 = *(const float4*)&bias[ll * 4];
    float o0 = acc.x * inv + b4.x, o1 = acc.y * inv + b4.y;
    float o2 = acc.z * inv + b4.z, o3 = acc.w * inv + b4.w;
    if (relu){ o0 = fmaxf(o0, 0.f); o1 = fmaxf(o1, 0.f); o2 = fmaxf(o2, 0.f); o3 = fmaxf(o3, 0.f); }
    if (OUTBF){
      ushort4 u; u.x = f2bf(o0); u.y = f2bf(o1); u.z = f2bf(o2); u.w = f2bf(o3);
      *(ushort4*)&outb[(size_t)node * D + ll * 4] = u;
    } else {
      *(float4*)&outf[(size_t)node * D + ll * 4] = make_float4(o0, o1, o2, o3);
    }
  }
}

// ---------------- fused pool + final linear ----------------
__device__ __forceinline__ int lbound(const int* a, int n, int key){
  int lo = 0, hi = n;
  while (lo < hi){ int mid = (lo + hi) >> 1; if (a[mid] < key) lo = mid + 1; else hi = mid; }
  return lo;
}

__global__ __launch_bounds__(128) void k_pool_final(const float* __restrict__ x,
                                                    const int* __restrict__ batch,
                                                    const float* __restrict__ Wl,
                                                    const float* __restrict__ bl,
                                                    float* __restrict__ out, int n){
  __shared__ float pl[128];
  int g = blockIdx.x;
  int c = threadIdx.x;
  int lo = lbound(batch, n, g);
  int hi = lbound(batch, n, g + 1);
  float sum = 0.f;
  for (int i = lo; i < hi; i++) sum += x[(size_t)i * D + c];
  float cnt = (float)(hi - lo);
  pl[c] = sum / fmaxf(cnt, 1.f);
  __syncthreads();
  float acc = bl[c];
#pragma unroll 4
  for (int k = 0; k < 128; k++) acc += pl[k] * Wl[(size_t)k * D + c];
  out[(size_t)g * D + c] = acc;
}

// ---------------- launch ----------------
extern "C" void kernel_launch(void* const* d_in, const int* in_sizes, int n_in,
                              void* d_out, int out_size, void* d_ws, size_t ws_size,
                              hipStream_t stream){
  const float* x     = (const float*)d_in[0];
  const int*   ei    = (const int*)d_in[1];
  const int*   batch = (const int*)d_in[3];
  const float* gW[3]  = {(const float*)d_in[4],  (const float*)d_in[8],  (const float*)d_in[12]};
  const float* gAs[3] = {(const float*)d_in[5],  (const float*)d_in[9],  (const float*)d_in[13]};
  const float* gAd[3] = {(const float*)d_in[6],  (const float*)d_in[10], (const float*)d_in[14]};
  const float* gB[3]  = {(const float*)d_in[7],  (const float*)d_in[11], (const float*)d_in[15]};
  const float* linW = (const float*)d_in[16];
  const float* linB = (const float*)d_in[17];
  float* outp = (float*)d_out;

  int N  = in_sizes[3];
  int E  = in_sizes[1] / 2;
  int EP = E + N;
  int G  = out_size / D;

  char* ws = (char*)d_ws;
  size_t off = 0;
  auto alloc = [&](size_t bytes)->void*{
    void* p = ws + off;
    off += (bytes + 255) & ~(size_t)255;
    return p;
  };
  float*    bufF   = (float*)alloc((size_t)N * D * 4);      // layer-3 agg out (fp32)
  ushort_t* bufB   = (ushort_t*)alloc((size_t)N * D * 2);   // layer-1/2 agg out (bf16)
  ushort_t* Hbf    = (ushort_t*)alloc((size_t)N * D * 2);   // h (bf16)
  float*    as_    = (float*)alloc((size_t)N * 4);
  float*    ad_    = (float*)alloc((size_t)N * 4);
  int*      counts = (int*)  alloc((size_t)N * 4);
  int*      cursor = (int*)  alloc((size_t)N * 4);
  int*      rowptr = (int*)  alloc((size_t)(N + 1) * 4);
  ushort_t* csr    = (ushort_t*)alloc((size_t)EP * 2);
  int*      bsum   = (int*)  alloc(1024 * 4);
  ushort_t* Wp[3];
  for (int i = 0; i < 3; i++) Wp[i] = (ushort_t*)alloc(2 * 16384 * 2);  // hi+lo packed
  (void)ws_size; (void)n_in;

  const int* esrc = ei;
  const int* edst = ei + E;

  int tpb = 256;
  int egrid = (EP + tpb - 1) / tpb;
  int ngrid = (N + tpb - 1) / tpb;

  k_zero <<<ngrid, tpb, 0, stream>>>(counts, N);
  k_hist <<<egrid, tpb, 0, stream>>>(edst, E, EP, counts);
  k_scan1<<<ngrid, tpb, 0, stream>>>(counts, N, rowptr, bsum);
  k_scan2<<<1,     tpb, 0, stream>>>(bsum, ngrid);
  k_scan3<<<ngrid, tpb, 0, stream>>>(rowptr, bsum, cursor, N, EP);
  k_fill <<<egrid, tpb, 0, stream>>>(esrc, edst, E, EP, cursor, csr);
  for (int i = 0; i < 3; i++)
    k_packW<<<64, tpb, 0, stream>>>(gW[i], Wp[i]);

  int gemm_grid = (N + 63) / 64;
  int node_grid = (N + 3) / 4;
  const uint2* hbu = (const uint2*)Hbf;

  // layer 1 (fp32 x in, bf16 h out)
  k_gemm_mfma<true> <<<gemm_grid, tpb, 0, stream>>>(x, Wp[0], gAs[0], gAd[0], Hbf, as_, ad_, N);
  k_agg<true>       <<<node_grid, tpb, 0, stream>>>(hbu, csr, rowptr, as_, ad_, gB[0], bufB, nullptr, 1, N);
  // layer 2 (bf16 in, bf16 out)
  k_gemm_mfma<false><<<gemm_grid, tpb, 0, stream>>>(bufB, Wp[1], gAs[1], gAd[1], Hbf, as_, ad_, N);
  k_agg<true>       <<<node_grid, tpb, 0, stream>>>(hbu, csr, rowptr, as_, ad_, gB[1], bufB, nullptr, 1, N);
  // layer 3 (bf16 in, fp32 out)
  k_gemm_mfma<false><<<gemm_grid, tpb, 0, stream>>>(bufB, Wp[2], gAs[2], gAd[2], Hbf, as_, ad_, N);
  k_agg<false>      <<<node_grid, tpb, 0, stream>>>(hbu, csr, rowptr, as_, ad_, gB[2], nullptr, bufF, 0, N);

  // fused pool + final linear
  k_pool_final<<<G, 128, 0, stream>>>(bufF, batch, linW, linB, outp, N);
}